// Round 2
// baseline (1316.037 us; speedup 1.0000x reference)
//
#include <hip/hip_runtime.h>
#include <hip/hip_bf16.h>

// ---------------- problem constants ----------------
constexpr int B = 65536;
constexpr int D = 512;
constexpr int E = 8;
constexpr int H = 2048;
constexpr int CT_ST = 140;   // epilogue LDS C-tile row stride (shorts); 2-way banks max

typedef __bf16 bf16x8 __attribute__((ext_vector_type(8)));
typedef float  f32x4  __attribute__((ext_vector_type(4)));

__device__ __forceinline__ unsigned short f2bf(float f) {
    unsigned u = __float_as_uint(f);
    u += 0x7FFFu + ((u >> 16) & 1u);   // round-to-nearest-even
    return (unsigned short)(u >> 16);
}

// async global->LDS DMA, 16 B per lane; global addr may be per-lane (gather OK),
// LDS dest = wave-uniform base + lane*16
__device__ __forceinline__ void dma16(const void* g, void* lds) {
    auto* gp = reinterpret_cast<const __attribute__((address_space(1))) unsigned*>(
        reinterpret_cast<uintptr_t>(g));
    auto* lp = reinterpret_cast<__attribute__((address_space(3))) unsigned*>(
        reinterpret_cast<uintptr_t>(lds));
    __builtin_amdgcn_global_load_lds(gp, lp, 16, 0, 0);
}

// ---------------- kernel: bulk x fp32 -> bf16 ----------------
__global__ __launch_bounds__(256) void convert_x(
    const float* __restrict__ x, unsigned short* __restrict__ xb) {
    const size_t i = ((size_t)blockIdx.x * 256 + threadIdx.x) * 8;
    const float4 v0 = *(const float4*)(x + i);
    const float4 v1 = *(const float4*)(x + i + 4);
    uint4 p;
    p.x = (unsigned)f2bf(v0.x) | ((unsigned)f2bf(v0.y) << 16);
    p.y = (unsigned)f2bf(v0.z) | ((unsigned)f2bf(v0.w) << 16);
    p.z = (unsigned)f2bf(v1.x) | ((unsigned)f2bf(v1.y) << 16);
    p.w = (unsigned)f2bf(v1.z) | ((unsigned)f2bf(v1.w) << 16);
    *(uint4*)(xb + i) = p;
}

// ---------------- kernel: router (thread per token) ----------------
__global__ __launch_bounds__(128) void router2(
    const float* __restrict__ x, const float* __restrict__ rw,
    const float* __restrict__ rb, unsigned* __restrict__ cnt,
    unsigned* __restrict__ tok_list, float* __restrict__ w_list) {
    __shared__ unsigned lcnt[E];
    __shared__ unsigned gbase[E];
    const int tid = threadIdx.x;
    if (tid < E) lcnt[tid] = 0u;
    __syncthreads();

    const int t = blockIdx.x * 128 + tid;
    const float4* xr = (const float4*)(x + (size_t)t * D);
    float acc[E];
#pragma unroll
    for (int e = 0; e < E; ++e) acc[e] = 0.f;

    for (int i = 0; i < D / 4; ++i) {
        const float4 xv = xr[i];
        const float* wr = rw + (size_t)i * 4 * E;   // wave-uniform -> s_load
#pragma unroll
        for (int e = 0; e < E; ++e) {
            acc[e] += xv.x * wr[e] + xv.y * wr[E + e] + xv.z * wr[2 * E + e]
                    + xv.w * wr[3 * E + e];
        }
    }
#pragma unroll
    for (int e = 0; e < E; ++e) acc[e] += rb[e];

    int e0 = 0; float l0 = acc[0];
#pragma unroll
    for (int e = 1; e < E; ++e) if (acc[e] > l0) { l0 = acc[e]; e0 = e; }
    int e1 = -1; float l1 = -3.4e38f;
#pragma unroll
    for (int e = 0; e < E; ++e)
        if (e != e0 && acc[e] > l1) { l1 = acc[e]; e1 = e; }

    const float w0 = 1.f / (1.f + expf(l1 - l0));   // renorm top-2 softmax
    const float w1v = 1.f - w0;

    const unsigned r0 = atomicAdd(&lcnt[e0], 1u);
    const unsigned r1 = atomicAdd(&lcnt[e1], 1u);
    __syncthreads();
    if (tid < E) gbase[tid] = atomicAdd(&cnt[tid], lcnt[tid]);
    __syncthreads();
    const unsigned s0 = gbase[e0] + r0;
    const unsigned s1 = gbase[e1] + r1;
    tok_list[(size_t)e0 * B + s0] = (unsigned)t;  w_list[(size_t)e0 * B + s0] = w0;
    tok_list[(size_t)e1 * B + s1] = (unsigned)t;  w_list[(size_t)e1 * B + s1] = w1v;
}

// ---------------- kernel: pad per-expert lists to multiple of 128 ----------------
__global__ __launch_bounds__(128) void pad_counts(
    const unsigned* __restrict__ cnt, unsigned* __restrict__ cntp,
    unsigned* __restrict__ tok_list, float* __restrict__ w_list, int cap) {
    const int tid = threadIdx.x;
    for (int e = 0; e < E; ++e) {
        const unsigned c = cnt[e];
        unsigned p = (c + 127u) & ~127u;
        if (p > (unsigned)cap) p = (unsigned)cap;
        if (c + tid < p) {
            tok_list[(size_t)e * B + c + tid] = 0u;   // valid token, weight 0
            w_list[(size_t)e * B + c + tid] = 0.f;
        }
        if (tid == 0) cntp[e] = p;
    }
}

// ---------------- kernel: fp32 [R][C] -> bf16 [C][R] transpose (per expert z) ----
__global__ __launch_bounds__(256) void transpose_bf16(
    const float* __restrict__ in, unsigned short* __restrict__ outp,
    int R, int C) {
    __shared__ unsigned short T[64][72];
    const int e = blockIdx.z;
    const int c0 = blockIdx.x * 64, r0 = blockIdx.y * 64;
    const float* ine = in + (size_t)e * R * C;
    unsigned short* oute = outp + (size_t)e * R * C;
    const int tid = threadIdx.x;
    const int rl = tid >> 2, cl = (tid & 3) * 16;

    const float* src = ine + (size_t)(r0 + rl) * C + c0 + cl;
    unsigned pk[8];
#pragma unroll
    for (int i = 0; i < 4; ++i) {
        const float4 v = *(const float4*)(src + i * 4);
        pk[2 * i]     = (unsigned)f2bf(v.x) | ((unsigned)f2bf(v.y) << 16);
        pk[2 * i + 1] = (unsigned)f2bf(v.z) | ((unsigned)f2bf(v.w) << 16);
    }
    *(uint4*)(&T[rl][cl])     = make_uint4(pk[0], pk[1], pk[2], pk[3]);
    *(uint4*)(&T[rl][cl + 8]) = make_uint4(pk[4], pk[5], pk[6], pk[7]);
    __syncthreads();

    unsigned po[8];
#pragma unroll
    for (int j = 0; j < 8; ++j) {
        po[j] = (unsigned)T[cl + 2 * j][rl] | ((unsigned)T[cl + 2 * j + 1][rl] << 16);
    }
    unsigned short* dst = oute + (size_t)(c0 + rl) * R + r0 + cl;
    *(uint4*)(dst)     = make_uint4(po[0], po[1], po[2], po[3]);
    *(uint4*)(dst + 8) = make_uint4(po[4], po[5], po[6], po[7]);
}

// ---------------- shared-memory layout for the stage kernel ----------------
// Triple-buffered A/B staging (48 KB) for prefetch depth 2 with counted vmcnt.
// The gemm1 epilogue C-tile (17.5 KB) is only live AFTER the K-loop's final
// barrier, so it aliases the staging bufs.
struct alignas(16) StageBufs {
    unsigned short A[3][128 * 32];    // 3 x 8 KB
    unsigned short Bm[3][128 * 32];   // 3 x 8 KB
};
union SmemU {
    StageBufs st;
    unsigned short Ct[64 * CT_ST];    // 17.5 KB, aliases st (epilogue only)
};

// ---------------- kernel: pipeline stage ----------------
// blockIdx.y <  4 : gemm2 for expert e_r : out[tok] += wgt * (hb_r[slot] @ w2s^T + b2)
// blockIdx.y >= 4 : gemm1 for expert e_w : hb_w[slot][H] = relu(xb[tok] @ w1s^T + b1)
// gemm2 blocks run 4x longer (K=2048 vs 512); HW dispatches x-fastest, so putting
// gemm2 at low y makes the long blocks start FIRST (longest-job-first packing).
//
// K-loop schedule (T3/T4 counted-vmcnt, depth-2 prefetch, 3 LDS buffers):
//   top of iter t: s_waitcnt vmcnt(4)   -> own 4 DMAs of tile t retired
//                  s_barrier            -> all waves' tile-t chunks in LDS
//                  issue tile t+2 DMAs into buf (t-1)%3  (safe: all waves'
//                  tile t-1 ds_reads retired before they crossed this barrier)
//                  ds_read tile t, MFMA (setprio-wrapped)
// Never drains vmcnt to 0 in steady state -> loads stay in flight across barriers.
//
// LDS bank swizzle (both-sides involution, rule #21): global source slot
// pc ^= (r4>>1)&3 at DMA; read slot q ^= (ln>>1)&3 at ds_read. Turns the
// 64B-row-stride ds_read_b128 pattern from 4-extra-cycle conflicts into 2-way (free).
__global__ __launch_bounds__(256, 4) void stage_kernel(
    const unsigned short* __restrict__ xb,
    const unsigned short* __restrict__ w1s, const unsigned short* __restrict__ w2s,
    const float* __restrict__ b1, const float* __restrict__ b2,
    const unsigned* __restrict__ cntp,
    const unsigned* __restrict__ tok_list, const float* __restrict__ w_list,
    unsigned short* __restrict__ hb_w, const unsigned short* __restrict__ hb_r,
    float* __restrict__ out, int e_w, int e_r) {
    __shared__ SmemU sm;
    __shared__ int   s_toks[128];
    __shared__ float s_wgts[128];
    const int tid = threadIdx.x, wv = tid >> 6, lane = tid & 63;
    const int ln = lane & 15, q = lane >> 4;
    const int wm = wv & 1, wn = wv >> 1;
    const int r4 = lane >> 2, pc = lane & 3;
    const int m0 = blockIdx.x * 128;
    const int dst0 = (wv * 2 + 0) * 512;   // wave-uniform LDS chunk offsets (shorts)
    const int dst1 = (wv * 2 + 1) * 512;
    const int qs  = q  ^ ((ln >> 1) & 3);  // swizzled read slot (lane-constant)
    const int pcs = pc ^ ((r4 >> 1) & 3);  // swizzled source slot (lane-constant)

    f32x4 acc[4][4];
#pragma unroll
    for (int i = 0; i < 4; ++i)
#pragma unroll
        for (int j = 0; j < 4; ++j) acc[i][j] = (f32x4){0.f, 0.f, 0.f, 0.f};

    if (blockIdx.y >= 4) {
        // ---------------- gemm1 ----------------
        if (e_w < 0) return;
        const int e = e_w;
        if ((unsigned)m0 >= cntp[e]) return;
        const int n0 = (blockIdx.y - 4) * 128;
        const size_t base = (size_t)e * B;
        constexpr int NT = D / 32;   // 16

        const unsigned ta0 = tok_list[base + m0 + (wv * 2 + 0) * 16 + r4];
        const unsigned ta1 = tok_list[base + m0 + (wv * 2 + 1) * 16 + r4];
        const unsigned short* ap0 = xb + (size_t)ta0 * D + pcs * 8;
        const unsigned short* ap1 = xb + (size_t)ta1 * D + pcs * 8;
        const unsigned short* w1e = w1s + (size_t)e * H * D;
        const unsigned short* bp0 = w1e + (size_t)(n0 + (wv * 2 + 0) * 16 + r4) * D + pcs * 8;
        const unsigned short* bp1 = w1e + (size_t)(n0 + (wv * 2 + 1) * 16 + r4) * D + pcs * 8;

        unsigned short *A0 = sm.st.A[0], *A1 = sm.st.A[1], *A2 = sm.st.A[2];
        unsigned short *B0 = sm.st.Bm[0], *B1 = sm.st.Bm[1], *B2 = sm.st.Bm[2];

        // prologue: stage tiles 0 and 1
        dma16(ap0, A0 + dst0);       dma16(ap1, A0 + dst1);
        dma16(bp0, B0 + dst0);       dma16(bp1, B0 + dst1);
        dma16(ap0 + 32, A1 + dst0);  dma16(ap1 + 32, A1 + dst1);
        dma16(bp0 + 32, B1 + dst0);  dma16(bp1 + 32, B1 + dst1);

        for (int t = 0; t < NT; ++t) {
            if (t + 1 < NT) { asm volatile("s_waitcnt vmcnt(4)" ::: "memory"); }
            else            { asm volatile("s_waitcnt vmcnt(0)" ::: "memory"); }
            __builtin_amdgcn_s_barrier();
            asm volatile("" ::: "memory");
            if (t + 2 < NT) {
                const int nk = (t + 2) * 32;
                dma16(ap0 + nk, A2 + dst0);  dma16(ap1 + nk, A2 + dst1);
                dma16(bp0 + nk, B2 + dst0);  dma16(bp1 + nk, B2 + dst1);
            }
            bf16x8 af[4], bfr[4];
#pragma unroll
            for (int i = 0; i < 4; ++i) {
                af[i]  = *(const bf16x8*)(A0 + (wm * 64 + i * 16 + ln) * 32 + qs * 8);
                bfr[i] = *(const bf16x8*)(B0 + (wn * 64 + i * 16 + ln) * 32 + qs * 8);
            }
            __builtin_amdgcn_s_setprio(1);
#pragma unroll
            for (int mt = 0; mt < 4; ++mt)
#pragma unroll
                for (int nt = 0; nt < 4; ++nt)
                    acc[mt][nt] = __builtin_amdgcn_mfma_f32_16x16x32_bf16(
                        af[mt], bfr[nt], acc[mt][nt], 0, 0, 0);
            __builtin_amdgcn_s_setprio(0);
            unsigned short* tp;
            tp = A0; A0 = A1; A1 = A2; A2 = tp;
            tp = B0; B0 = B1; B1 = B2; B2 = tp;
        }
        __syncthreads();   // all ds_reads done before Ct aliases the buffers

        // epilogue: bias+relu, stage 64-row chunks in LDS (aliases staging bufs),
        // coalesced 16B stores
        float b1v[4];
#pragma unroll
        for (int nt = 0; nt < 4; ++nt)
            b1v[nt] = b1[(size_t)e * H + n0 + wn * 64 + nt * 16 + ln];

#pragma unroll
        for (int c = 0; c < 2; ++c) {
            if (wm == c) {
#pragma unroll
                for (int mt = 0; mt < 4; ++mt)
#pragma unroll
                    for (int nt = 0; nt < 4; ++nt)
#pragma unroll
                        for (int r = 0; r < 4; ++r) {
                            const int lr = mt * 16 + q * 4 + r;
                            float v = acc[mt][nt][r] + b1v[nt];
                            v = v > 0.f ? v : 0.f;
                            sm.Ct[lr * CT_ST + wn * 64 + nt * 16 + ln] = f2bf(v);
                        }
            }
            __syncthreads();
            {
                const int lr = tid >> 2, seg = tid & 3;
                const unsigned short* csrc = sm.Ct + lr * CT_ST + seg * 32;
                unsigned short* gdst = hb_w + (size_t)(m0 + c * 64 + lr) * H + n0 + seg * 32;
#pragma unroll
                for (int u = 0; u < 4; ++u)
                    *(uint4*)(gdst + u * 8) = *(const uint4*)(csrc + u * 8);
            }
            __syncthreads();
        }
    } else {
        // ---------------- gemm2 ----------------
        if (e_r < 0) return;
        const int e = e_r;
        if ((unsigned)m0 >= cntp[e]) return;
        const int n0 = blockIdx.y * 128;
        const size_t base = (size_t)e * B;
        constexpr int NT = H / 32;   // 64

        if (tid < 128) {
            s_toks[tid] = (int)tok_list[base + m0 + tid];
            s_wgts[tid] = w_list[base + m0 + tid];
        }
        const unsigned short* ap0 = hb_r + (size_t)(m0 + (wv * 2 + 0) * 16 + r4) * H + pcs * 8;
        const unsigned short* ap1 = hb_r + (size_t)(m0 + (wv * 2 + 1) * 16 + r4) * H + pcs * 8;
        const unsigned short* w2e = w2s + (size_t)e * D * H;
        const unsigned short* bp0 = w2e + (size_t)(n0 + (wv * 2 + 0) * 16 + r4) * H + pcs * 8;
        const unsigned short* bp1 = w2e + (size_t)(n0 + (wv * 2 + 1) * 16 + r4) * H + pcs * 8;

        unsigned short *A0 = sm.st.A[0], *A1 = sm.st.A[1], *A2 = sm.st.A[2];
        unsigned short *B0 = sm.st.Bm[0], *B1 = sm.st.Bm[1], *B2 = sm.st.Bm[2];

        dma16(ap0, A0 + dst0);       dma16(ap1, A0 + dst1);
        dma16(bp0, B0 + dst0);       dma16(bp1, B0 + dst1);
        dma16(ap0 + 32, A1 + dst0);  dma16(ap1 + 32, A1 + dst1);
        dma16(bp0 + 32, B1 + dst0);  dma16(bp1 + 32, B1 + dst1);

        for (int t = 0; t < NT; ++t) {
            if (t + 1 < NT) { asm volatile("s_waitcnt vmcnt(4)" ::: "memory"); }
            else            { asm volatile("s_waitcnt vmcnt(0)" ::: "memory"); }
            __builtin_amdgcn_s_barrier();
            asm volatile("" ::: "memory");
            if (t + 2 < NT) {
                const int nk = (t + 2) * 32;
                dma16(ap0 + nk, A2 + dst0);  dma16(ap1 + nk, A2 + dst1);
                dma16(bp0 + nk, B2 + dst0);  dma16(bp1 + nk, B2 + dst1);
            }
            bf16x8 af[4], bfr[4];
#pragma unroll
            for (int i = 0; i < 4; ++i) {
                af[i]  = *(const bf16x8*)(A0 + (wm * 64 + i * 16 + ln) * 32 + qs * 8);
                bfr[i] = *(const bf16x8*)(B0 + (wn * 64 + i * 16 + ln) * 32 + qs * 8);
            }
            __builtin_amdgcn_s_setprio(1);
#pragma unroll
            for (int mt = 0; mt < 4; ++mt)
#pragma unroll
                for (int nt = 0; nt < 4; ++nt)
                    acc[mt][nt] = __builtin_amdgcn_mfma_f32_16x16x32_bf16(
                        af[mt], bfr[nt], acc[mt][nt], 0, 0, 0);
            __builtin_amdgcn_s_setprio(0);
            unsigned short* tp;
            tp = A0; A0 = A1; A1 = A2; A2 = tp;
            tp = B0; B0 = B1; B1 = B2; B2 = tp;
        }
        __syncthreads();

        float b2v[4];
#pragma unroll
        for (int nt = 0; nt < 4; ++nt)
            b2v[nt] = b2[(size_t)e * D + n0 + wn * 64 + nt * 16 + ln];

#pragma unroll
        for (int mt = 0; mt < 4; ++mt) {
#pragma unroll
            for (int r = 0; r < 4; ++r) {
                const int m = wm * 64 + mt * 16 + q * 4 + r;
                const float wgt = s_wgts[m];
                if (wgt != 0.f) {                 // skip pad rows (avoids token-0 RMW race)
                    const int tok = s_toks[m];
                    float* orow = out + (size_t)tok * D + n0 + wn * 64 + ln;
#pragma unroll
                    for (int nt = 0; nt < 4; ++nt)
                        orow[nt * 16] += wgt * (acc[mt][nt][r] + b2v[nt]);
                }
            }
        }
    }
}

// ---------------- launch ----------------
extern "C" void kernel_launch(void* const* d_in, const int* in_sizes, int n_in,
                              void* d_out, int out_size, void* d_ws, size_t ws_size,
                              hipStream_t stream) {
    const float* x  = (const float*)d_in[0];
    const float* rw = (const float*)d_in[1];
    const float* rb = (const float*)d_in[2];
    const float* w1 = (const float*)d_in[3];
    const float* b1 = (const float*)d_in[4];
    const float* w2 = (const float*)d_in[5];
    const float* b2 = (const float*)d_in[6];
    float* out = (float*)d_out;

    char* ws = (char*)d_ws;
    const size_t off_tok = 1024;
    const size_t off_wl  = off_tok + (size_t)E * B * 4;
    const size_t off_w1s = off_wl  + (size_t)E * B * 4;
    const size_t off_w2s = off_w1s + (size_t)E * D * H * 2;
    const size_t off_xb  = off_w2s + (size_t)E * D * H * 2;
    const size_t off_hb  = off_xb  + (size_t)B * D * 2;

    unsigned* cnt      = (unsigned*)ws;
    unsigned* cntp     = (unsigned*)(ws + 256);
    unsigned* tok_list = (unsigned*)(ws + off_tok);
    float*    w_list   = (float*)(ws + off_wl);
    unsigned short* w1s = (unsigned short*)(ws + off_w1s);
    unsigned short* w2s = (unsigned short*)(ws + off_w2s);
    unsigned short* xb  = (unsigned short*)(ws + off_xb);

    // workspace-driven config (deterministic per call -> graph-safe)
    const size_t rem = (ws_size > off_hb) ? (ws_size - off_hb) : 0;
    const size_t hrow = (size_t)H * 2;
    int cap; bool pipelined;
    {
        size_t cp = (rem / 2 / hrow) & ~(size_t)127;
        if (cp > 24576) cp = 24576;
        if (cp >= 20480) { pipelined = true; cap = (int)cp; }
        else {
            pipelined = false;
            size_t cs = (rem / hrow) & ~(size_t)127;
            if (cs > 24576) cs = 24576;
            cap = (int)cs;
        }
    }
    unsigned short* hb0 = (unsigned short*)(ws + off_hb);
    unsigned short* hb1 = pipelined ? hb0 + (size_t)cap * H : hb0;

    hipMemsetAsync(ws, 0, 1024, stream);                                  // counters
    hipMemsetAsync(d_out, 0, (size_t)out_size * sizeof(float), stream);   // fp32 zeros

    convert_x<<<(B * D) / 2048, 256, 0, stream>>>(x, xb);
    transpose_bf16<<<dim3(H / 64, D / 64, E), 256, 0, stream>>>(w1, w1s, D, H);
    transpose_bf16<<<dim3(D / 64, H / 64, E), 256, 0, stream>>>(w2, w2s, H, D);
    router2<<<B / 128, 128, 0, stream>>>(x, rw, rb, cnt, tok_list, w_list);
    pad_counts<<<1, 128, 0, stream>>>(cnt, cntp, tok_list, w_list, cap);

    const dim3 sgrid(cap / 128, 20);   // y<4: gemm2 (long blocks first), y>=4: gemm1
    if (pipelined) {
        for (int s = 0; s <= E; ++s) {
            unsigned short* hw = (s & 1) ? hb1 : hb0;
            unsigned short* hr = (s & 1) ? hb0 : hb1;
            stage_kernel<<<sgrid, 256, 0, stream>>>(
                xb, w1s, w2s, b1, b2, cntp, tok_list, w_list,
                hw, hr, out, (s < E) ? s : -1, (s > 0) ? s - 1 : -1);
        }
    } else {
        for (int e = 0; e < E; ++e) {
            stage_kernel<<<sgrid, 256, 0, stream>>>(
                xb, w1s, w2s, b1, b2, cntp, tok_list, w_list,
                hb0, hb0, out, e, -1);
            stage_kernel<<<sgrid, 256, 0, stream>>>(
                xb, w1s, w2s, b1, b2, cntp, tok_list, w_list,
                hb0, hb0, out, -1, e);
        }
    }
}

// Round 3
// 1255.197 us; speedup vs baseline: 1.0485x; 1.0485x over previous
//
#include <hip/hip_runtime.h>
#include <hip/hip_bf16.h>

// ---------------- problem constants ----------------
constexpr int B = 65536;
constexpr int D = 512;
constexpr int E = 8;
constexpr int H = 2048;
constexpr int CT_ST = 140;   // epilogue LDS C-tile row stride (shorts); 2-way banks max

typedef __bf16 bf16x8 __attribute__((ext_vector_type(8)));
typedef float  f32x4  __attribute__((ext_vector_type(4)));

__device__ __forceinline__ unsigned short f2bf(float f) {
    unsigned u = __float_as_uint(f);
    u += 0x7FFFu + ((u >> 16) & 1u);   // round-to-nearest-even
    return (unsigned short)(u >> 16);
}

// async global->LDS DMA, 16 B per lane; global addr may be per-lane (gather OK),
// LDS dest = wave-uniform base + lane*16
__device__ __forceinline__ void dma16(const void* g, void* lds) {
    auto* gp = reinterpret_cast<const __attribute__((address_space(1))) unsigned*>(
        reinterpret_cast<uintptr_t>(g));
    auto* lp = reinterpret_cast<__attribute__((address_space(3))) unsigned*>(
        reinterpret_cast<uintptr_t>(lds));
    __builtin_amdgcn_global_load_lds(gp, lp, 16, 0, 0);
}

// ---------------- kernel: bulk x fp32 -> bf16 ----------------
__global__ __launch_bounds__(256) void convert_x(
    const float* __restrict__ x, unsigned short* __restrict__ xb) {
    const size_t i = ((size_t)blockIdx.x * 256 + threadIdx.x) * 8;
    const float4 v0 = *(const float4*)(x + i);
    const float4 v1 = *(const float4*)(x + i + 4);
    uint4 p;
    p.x = (unsigned)f2bf(v0.x) | ((unsigned)f2bf(v0.y) << 16);
    p.y = (unsigned)f2bf(v0.z) | ((unsigned)f2bf(v0.w) << 16);
    p.z = (unsigned)f2bf(v1.x) | ((unsigned)f2bf(v1.y) << 16);
    p.w = (unsigned)f2bf(v1.z) | ((unsigned)f2bf(v1.w) << 16);
    *(uint4*)(xb + i) = p;
}

// ---------------- kernel: router (thread per token) ----------------
__global__ __launch_bounds__(128) void router2(
    const float* __restrict__ x, const float* __restrict__ rw,
    const float* __restrict__ rb, unsigned* __restrict__ cnt,
    unsigned* __restrict__ tok_list, float* __restrict__ w_list) {
    __shared__ unsigned lcnt[E];
    __shared__ unsigned gbase[E];
    const int tid = threadIdx.x;
    if (tid < E) lcnt[tid] = 0u;
    __syncthreads();

    const int t = blockIdx.x * 128 + tid;
    const float4* xr = (const float4*)(x + (size_t)t * D);
    float acc[E];
#pragma unroll
    for (int e = 0; e < E; ++e) acc[e] = 0.f;

    for (int i = 0; i < D / 4; ++i) {
        const float4 xv = xr[i];
        const float* wr = rw + (size_t)i * 4 * E;   // wave-uniform -> s_load
#pragma unroll
        for (int e = 0; e < E; ++e) {
            acc[e] += xv.x * wr[e] + xv.y * wr[E + e] + xv.z * wr[2 * E + e]
                    + xv.w * wr[3 * E + e];
        }
    }
#pragma unroll
    for (int e = 0; e < E; ++e) acc[e] += rb[e];

    int e0 = 0; float l0 = acc[0];
#pragma unroll
    for (int e = 1; e < E; ++e) if (acc[e] > l0) { l0 = acc[e]; e0 = e; }
    int e1 = -1; float l1 = -3.4e38f;
#pragma unroll
    for (int e = 0; e < E; ++e)
        if (e != e0 && acc[e] > l1) { l1 = acc[e]; e1 = e; }

    const float w0 = 1.f / (1.f + expf(l1 - l0));   // renorm top-2 softmax
    const float w1v = 1.f - w0;

    const unsigned r0 = atomicAdd(&lcnt[e0], 1u);
    const unsigned r1 = atomicAdd(&lcnt[e1], 1u);
    __syncthreads();
    if (tid < E) gbase[tid] = atomicAdd(&cnt[tid], lcnt[tid]);
    __syncthreads();
    const unsigned s0 = gbase[e0] + r0;
    const unsigned s1 = gbase[e1] + r1;
    tok_list[(size_t)e0 * B + s0] = (unsigned)t;  w_list[(size_t)e0 * B + s0] = w0;
    tok_list[(size_t)e1 * B + s1] = (unsigned)t;  w_list[(size_t)e1 * B + s1] = w1v;
}

// ---------------- kernel: pad per-expert lists to multiple of 128 ----------------
__global__ __launch_bounds__(128) void pad_counts(
    const unsigned* __restrict__ cnt, unsigned* __restrict__ cntp,
    unsigned* __restrict__ tok_list, float* __restrict__ w_list, int cap) {
    const int tid = threadIdx.x;
    for (int e = 0; e < E; ++e) {
        const unsigned c = cnt[e];
        unsigned p = (c + 127u) & ~127u;
        if (p > (unsigned)cap) p = (unsigned)cap;
        if (c + tid < p) {
            tok_list[(size_t)e * B + c + tid] = 0u;   // valid token, weight 0
            w_list[(size_t)e * B + c + tid] = 0.f;
        }
        if (tid == 0) cntp[e] = p;
    }
}

// ---------------- kernel: fp32 [R][C] -> bf16 [C][R] transpose (per expert z) ----
__global__ __launch_bounds__(256) void transpose_bf16(
    const float* __restrict__ in, unsigned short* __restrict__ outp,
    int R, int C) {
    __shared__ unsigned short T[64][72];
    const int e = blockIdx.z;
    const int c0 = blockIdx.x * 64, r0 = blockIdx.y * 64;
    const float* ine = in + (size_t)e * R * C;
    unsigned short* oute = outp + (size_t)e * R * C;
    const int tid = threadIdx.x;
    const int rl = tid >> 2, cl = (tid & 3) * 16;

    const float* src = ine + (size_t)(r0 + rl) * C + c0 + cl;
    unsigned pk[8];
#pragma unroll
    for (int i = 0; i < 4; ++i) {
        const float4 v = *(const float4*)(src + i * 4);
        pk[2 * i]     = (unsigned)f2bf(v.x) | ((unsigned)f2bf(v.y) << 16);
        pk[2 * i + 1] = (unsigned)f2bf(v.z) | ((unsigned)f2bf(v.w) << 16);
    }
    *(uint4*)(&T[rl][cl])     = make_uint4(pk[0], pk[1], pk[2], pk[3]);
    *(uint4*)(&T[rl][cl + 8]) = make_uint4(pk[4], pk[5], pk[6], pk[7]);
    __syncthreads();

    unsigned po[8];
#pragma unroll
    for (int j = 0; j < 8; ++j) {
        po[j] = (unsigned)T[cl + 2 * j][rl] | ((unsigned)T[cl + 2 * j + 1][rl] << 16);
    }
    unsigned short* dst = oute + (size_t)(c0 + rl) * R + r0 + cl;
    *(uint4*)(dst)     = make_uint4(po[0], po[1], po[2], po[3]);
    *(uint4*)(dst + 8) = make_uint4(po[4], po[5], po[6], po[7]);
}

// ---------------- shared-memory layout for the stage kernel ----------------
// Double-buffered A/B staging (32 KB) -> 4 blocks/CU residency (the round-2
// 3-buffer variant cost a block/CU and regressed; TLP dominates here).
// The gemm1 epilogue C-tile (17.5 KB) is only live AFTER the K-loop's final
// barrier, so it aliases the staging bufs.
struct alignas(16) StageBufs {
    unsigned short A[2][128 * 32];    // 2 x 8 KB
    unsigned short Bm[2][128 * 32];   // 2 x 8 KB
};
union SmemU {
    StageBufs st;
    unsigned short Ct[64 * CT_ST];    // 17.5 KB, aliases st (epilogue only)
};

// ---------------- kernel: pipeline stage ----------------
// blockIdx.y <  4 : gemm2 for expert e_r : out[tok] += wgt * (hb_r[slot] @ w2s^T + b2)
// blockIdx.y >= 4 : gemm1 for expert e_w : hb_w[slot][H] = relu(xb[tok] @ w1s^T + b1)
// gemm2 blocks run 4x longer (K=2048 vs 512); HW dispatches x-fastest, so putting
// gemm2 at low y makes the long blocks start FIRST (longest-job-first packing).
//
// K-loop schedule (2-buffer, full-iteration cover):
//   top of iter t: s_waitcnt vmcnt(0)  -> tile t resident (its DMAs were issued
//                                         one FULL iteration ago; ~350cy cover,
//                                         nothing else is in flight at this point)
//                  s_barrier           -> all waves' tile-t chunks in LDS
//                  issue tile t+1 DMAs into buf^1 (safe: buf^1's iter-(t-1)
//                  ds_reads retired before every wave crossed this barrier)
//                  ds_read tile t, MFMA (setprio-wrapped)
// vs round 1 (issue-then-drain in the same iter, only MFMA-time of cover) this
// doubles the latency cover without the third buffer's occupancy cost.
//
// LDS bank swizzle (both-sides involution, rule #21): global source slot
// pc ^= (r4>>1)&3 at DMA; read slot q ^= (ln>>1)&3 at ds_read. Measured: kills
// all SQ_LDS_BANK_CONFLICT (8.5M -> 0) at zero instruction cost.
__global__ __launch_bounds__(256, 4) void stage_kernel(
    const unsigned short* __restrict__ xb,
    const unsigned short* __restrict__ w1s, const unsigned short* __restrict__ w2s,
    const float* __restrict__ b1, const float* __restrict__ b2,
    const unsigned* __restrict__ cntp,
    const unsigned* __restrict__ tok_list, const float* __restrict__ w_list,
    unsigned short* __restrict__ hb_w, const unsigned short* __restrict__ hb_r,
    float* __restrict__ out, int e_w, int e_r) {
    __shared__ SmemU sm;
    __shared__ int   s_toks[128];
    __shared__ float s_wgts[128];
    const int tid = threadIdx.x, wv = tid >> 6, lane = tid & 63;
    const int ln = lane & 15, q = lane >> 4;
    const int wm = wv & 1, wn = wv >> 1;
    const int r4 = lane >> 2, pc = lane & 3;
    const int m0 = blockIdx.x * 128;
    const int dst0 = (wv * 2 + 0) * 512;   // wave-uniform LDS chunk offsets (shorts)
    const int dst1 = (wv * 2 + 1) * 512;
    const int qs  = q  ^ ((ln >> 1) & 3);  // swizzled read slot (lane-constant)
    const int pcs = pc ^ ((r4 >> 1) & 3);  // swizzled source slot (lane-constant)

    f32x4 acc[4][4];
#pragma unroll
    for (int i = 0; i < 4; ++i)
#pragma unroll
        for (int j = 0; j < 4; ++j) acc[i][j] = (f32x4){0.f, 0.f, 0.f, 0.f};

    if (blockIdx.y >= 4) {
        // ---------------- gemm1 ----------------
        if (e_w < 0) return;
        const int e = e_w;
        if ((unsigned)m0 >= cntp[e]) return;
        const int n0 = (blockIdx.y - 4) * 128;
        const size_t base = (size_t)e * B;
        constexpr int NT = D / 32;   // 16

        const unsigned ta0 = tok_list[base + m0 + (wv * 2 + 0) * 16 + r4];
        const unsigned ta1 = tok_list[base + m0 + (wv * 2 + 1) * 16 + r4];
        const unsigned short* ap0 = xb + (size_t)ta0 * D + pcs * 8;
        const unsigned short* ap1 = xb + (size_t)ta1 * D + pcs * 8;
        const unsigned short* w1e = w1s + (size_t)e * H * D;
        const unsigned short* bp0 = w1e + (size_t)(n0 + (wv * 2 + 0) * 16 + r4) * D + pcs * 8;
        const unsigned short* bp1 = w1e + (size_t)(n0 + (wv * 2 + 1) * 16 + r4) * D + pcs * 8;

        unsigned short *A0 = sm.st.A[0], *A1 = sm.st.A[1];
        unsigned short *B0 = sm.st.Bm[0], *B1 = sm.st.Bm[1];

        // prologue: stage tile 0
        dma16(ap0, A0 + dst0);  dma16(ap1, A0 + dst1);
        dma16(bp0, B0 + dst0);  dma16(bp1, B0 + dst1);

        for (int t = 0; t < NT; ++t) {
            asm volatile("s_waitcnt vmcnt(0)" ::: "memory");
            __builtin_amdgcn_s_barrier();
            asm volatile("" ::: "memory");
            if (t + 1 < NT) {
                const int nk = (t + 1) * 32;
                dma16(ap0 + nk, A1 + dst0);  dma16(ap1 + nk, A1 + dst1);
                dma16(bp0 + nk, B1 + dst0);  dma16(bp1 + nk, B1 + dst1);
            }
            bf16x8 af[4], bfr[4];
#pragma unroll
            for (int i = 0; i < 4; ++i) {
                af[i]  = *(const bf16x8*)(A0 + (wm * 64 + i * 16 + ln) * 32 + qs * 8);
                bfr[i] = *(const bf16x8*)(B0 + (wn * 64 + i * 16 + ln) * 32 + qs * 8);
            }
            __builtin_amdgcn_s_setprio(1);
#pragma unroll
            for (int mt = 0; mt < 4; ++mt)
#pragma unroll
                for (int nt = 0; nt < 4; ++nt)
                    acc[mt][nt] = __builtin_amdgcn_mfma_f32_16x16x32_bf16(
                        af[mt], bfr[nt], acc[mt][nt], 0, 0, 0);
            __builtin_amdgcn_s_setprio(0);
            unsigned short* tp;
            tp = A0; A0 = A1; A1 = tp;
            tp = B0; B0 = B1; B1 = tp;
        }
        __syncthreads();   // all ds_reads done before Ct aliases the buffers

        // epilogue: bias+relu, stage 64-row chunks in LDS (aliases staging bufs),
        // coalesced 16B stores
        float b1v[4];
#pragma unroll
        for (int nt = 0; nt < 4; ++nt)
            b1v[nt] = b1[(size_t)e * H + n0 + wn * 64 + nt * 16 + ln];

#pragma unroll
        for (int c = 0; c < 2; ++c) {
            if (wm == c) {
#pragma unroll
                for (int mt = 0; mt < 4; ++mt)
#pragma unroll
                    for (int nt = 0; nt < 4; ++nt)
#pragma unroll
                        for (int r = 0; r < 4; ++r) {
                            const int lr = mt * 16 + q * 4 + r;
                            float v = acc[mt][nt][r] + b1v[nt];
                            v = v > 0.f ? v : 0.f;
                            sm.Ct[lr * CT_ST + wn * 64 + nt * 16 + ln] = f2bf(v);
                        }
            }
            __syncthreads();
            {
                const int lr = tid >> 2, seg = tid & 3;
                const unsigned short* csrc = sm.Ct + lr * CT_ST + seg * 32;
                unsigned short* gdst = hb_w + (size_t)(m0 + c * 64 + lr) * H + n0 + seg * 32;
#pragma unroll
                for (int u = 0; u < 4; ++u)
                    *(uint4*)(gdst + u * 8) = *(const uint4*)(csrc + u * 8);
            }
            __syncthreads();
        }
    } else {
        // ---------------- gemm2 ----------------
        if (e_r < 0) return;
        const int e = e_r;
        if ((unsigned)m0 >= cntp[e]) return;
        const int n0 = blockIdx.y * 128;
        const size_t base = (size_t)e * B;
        constexpr int NT = H / 32;   // 64

        if (tid < 128) {
            s_toks[tid] = (int)tok_list[base + m0 + tid];
            s_wgts[tid] = w_list[base + m0 + tid];
        }
        const unsigned short* ap0 = hb_r + (size_t)(m0 + (wv * 2 + 0) * 16 + r4) * H + pcs * 8;
        const unsigned short* ap1 = hb_r + (size_t)(m0 + (wv * 2 + 1) * 16 + r4) * H + pcs * 8;
        const unsigned short* w2e = w2s + (size_t)e * D * H;
        const unsigned short* bp0 = w2e + (size_t)(n0 + (wv * 2 + 0) * 16 + r4) * H + pcs * 8;
        const unsigned short* bp1 = w2e + (size_t)(n0 + (wv * 2 + 1) * 16 + r4) * H + pcs * 8;

        unsigned short *A0 = sm.st.A[0], *A1 = sm.st.A[1];
        unsigned short *B0 = sm.st.Bm[0], *B1 = sm.st.Bm[1];

        dma16(ap0, A0 + dst0);  dma16(ap1, A0 + dst1);
        dma16(bp0, B0 + dst0);  dma16(bp1, B0 + dst1);

        for (int t = 0; t < NT; ++t) {
            asm volatile("s_waitcnt vmcnt(0)" ::: "memory");
            __builtin_amdgcn_s_barrier();
            asm volatile("" ::: "memory");
            if (t + 1 < NT) {
                const int nk = (t + 1) * 32;
                dma16(ap0 + nk, A1 + dst0);  dma16(ap1 + nk, A1 + dst1);
                dma16(bp0 + nk, B1 + dst0);  dma16(bp1 + nk, B1 + dst1);
            }
            bf16x8 af[4], bfr[4];
#pragma unroll
            for (int i = 0; i < 4; ++i) {
                af[i]  = *(const bf16x8*)(A0 + (wm * 64 + i * 16 + ln) * 32 + qs * 8);
                bfr[i] = *(const bf16x8*)(B0 + (wn * 64 + i * 16 + ln) * 32 + qs * 8);
            }
            __builtin_amdgcn_s_setprio(1);
#pragma unroll
            for (int mt = 0; mt < 4; ++mt)
#pragma unroll
                for (int nt = 0; nt < 4; ++nt)
                    acc[mt][nt] = __builtin_amdgcn_mfma_f32_16x16x32_bf16(
                        af[mt], bfr[nt], acc[mt][nt], 0, 0, 0);
            __builtin_amdgcn_s_setprio(0);
            unsigned short* tp;
            tp = A0; A0 = A1; A1 = tp;
            tp = B0; B0 = B1; B1 = tp;
        }
        __syncthreads();

        float b2v[4];
#pragma unroll
        for (int nt = 0; nt < 4; ++nt)
            b2v[nt] = b2[(size_t)e * D + n0 + wn * 64 + nt * 16 + ln];

#pragma unroll
        for (int mt = 0; mt < 4; ++mt) {
#pragma unroll
            for (int r = 0; r < 4; ++r) {
                const int m = wm * 64 + mt * 16 + q * 4 + r;
                const float wgt = s_wgts[m];
                if (wgt != 0.f) {                 // skip pad rows (avoids token-0 RMW race)
                    const int tok = s_toks[m];
                    float* orow = out + (size_t)tok * D + n0 + wn * 64 + ln;
#pragma unroll
                    for (int nt = 0; nt < 4; ++nt)
                        orow[nt * 16] += wgt * (acc[mt][nt][r] + b2v[nt]);
                }
            }
        }
    }
}

// ---------------- launch ----------------
extern "C" void kernel_launch(void* const* d_in, const int* in_sizes, int n_in,
                              void* d_out, int out_size, void* d_ws, size_t ws_size,
                              hipStream_t stream) {
    const float* x  = (const float*)d_in[0];
    const float* rw = (const float*)d_in[1];
    const float* rb = (const float*)d_in[2];
    const float* w1 = (const float*)d_in[3];
    const float* b1 = (const float*)d_in[4];
    const float* w2 = (const float*)d_in[5];
    const float* b2 = (const float*)d_in[6];
    float* out = (float*)d_out;

    char* ws = (char*)d_ws;
    const size_t off_tok = 1024;
    const size_t off_wl  = off_tok + (size_t)E * B * 4;
    const size_t off_w1s = off_wl  + (size_t)E * B * 4;
    const size_t off_w2s = off_w1s + (size_t)E * D * H * 2;
    const size_t off_xb  = off_w2s + (size_t)E * D * H * 2;
    const size_t off_hb  = off_xb  + (size_t)B * D * 2;

    unsigned* cnt      = (unsigned*)ws;
    unsigned* cntp     = (unsigned*)(ws + 256);
    unsigned* tok_list = (unsigned*)(ws + off_tok);
    float*    w_list   = (float*)(ws + off_wl);
    unsigned short* w1s = (unsigned short*)(ws + off_w1s);
    unsigned short* w2s = (unsigned short*)(ws + off_w2s);
    unsigned short* xb  = (unsigned short*)(ws + off_xb);

    // workspace-driven config (deterministic per call -> graph-safe)
    const size_t rem = (ws_size > off_hb) ? (ws_size - off_hb) : 0;
    const size_t hrow = (size_t)H * 2;
    int cap; bool pipelined;
    {
        size_t cp = (rem / 2 / hrow) & ~(size_t)127;
        if (cp > 24576) cp = 24576;
        if (cp >= 20480) { pipelined = true; cap = (int)cp; }
        else {
            pipelined = false;
            size_t cs = (rem / hrow) & ~(size_t)127;
            if (cs > 24576) cs = 24576;
            cap = (int)cs;
        }
    }
    unsigned short* hb0 = (unsigned short*)(ws + off_hb);
    unsigned short* hb1 = pipelined ? hb0 + (size_t)cap * H : hb0;

    hipMemsetAsync(ws, 0, 1024, stream);                                  // counters
    hipMemsetAsync(d_out, 0, (size_t)out_size * sizeof(float), stream);   // fp32 zeros

    convert_x<<<(B * D) / 2048, 256, 0, stream>>>(x, xb);
    transpose_bf16<<<dim3(H / 64, D / 64, E), 256, 0, stream>>>(w1, w1s, D, H);
    transpose_bf16<<<dim3(D / 64, H / 64, E), 256, 0, stream>>>(w2, w2s, H, D);
    router2<<<B / 128, 128, 0, stream>>>(x, rw, rb, cnt, tok_list, w_list);
    pad_counts<<<1, 128, 0, stream>>>(cnt, cntp, tok_list, w_list, cap);

    const dim3 sgrid(cap / 128, 20);   // y<4: gemm2 (long blocks first), y>=4: gemm1
    if (pipelined) {
        for (int s = 0; s <= E; ++s) {
            unsigned short* hw = (s & 1) ? hb1 : hb0;
            unsigned short* hr = (s & 1) ? hb0 : hb1;
            stage_kernel<<<sgrid, 256, 0, stream>>>(
                xb, w1s, w2s, b1, b2, cntp, tok_list, w_list,
                hw, hr, out, (s < E) ? s : -1, (s > 0) ? s - 1 : -1);
        }
    } else {
        for (int e = 0; e < E; ++e) {
            stage_kernel<<<sgrid, 256, 0, stream>>>(
                xb, w1s, w2s, b1, b2, cntp, tok_list, w_list,
                hb0, hb0, out, e, -1);
            stage_kernel<<<sgrid, 256, 0, stream>>>(
                xb, w1s, w2s, b1, b2, cntp, tok_list, w_list,
                hb0, hb0, out, -1, e);
        }
    }
}

// Round 4
// 1151.008 us; speedup vs baseline: 1.1434x; 1.0905x over previous
//
#include <hip/hip_runtime.h>
#include <hip/hip_bf16.h>

// ---------------- problem constants ----------------
constexpr int B = 65536;
constexpr int D = 512;
constexpr int E = 8;
constexpr int H = 2048;
constexpr int CT_ST = 140;   // epilogue LDS C-tile row stride (shorts)

typedef __bf16 bf16x8 __attribute__((ext_vector_type(8)));
typedef float  f32x4  __attribute__((ext_vector_type(4)));

__device__ __forceinline__ unsigned short f2bf(float f) {
    unsigned u = __float_as_uint(f);
    u += 0x7FFFu + ((u >> 16) & 1u);   // round-to-nearest-even
    return (unsigned short)(u >> 16);
}

// async global->LDS DMA, 16 B per lane; global addr may be per-lane (gather OK),
// LDS dest = wave-uniform base + lane*16
__device__ __forceinline__ void dma16(const void* g, void* lds) {
    auto* gp = reinterpret_cast<const __attribute__((address_space(1))) unsigned*>(
        reinterpret_cast<uintptr_t>(g));
    auto* lp = reinterpret_cast<__attribute__((address_space(3))) unsigned*>(
        reinterpret_cast<uintptr_t>(lds));
    __builtin_amdgcn_global_load_lds(gp, lp, 16, 0, 0);
}

// ---------------- kernel: bulk x fp32 -> bf16 ----------------
__global__ __launch_bounds__(256) void convert_x(
    const float* __restrict__ x, unsigned short* __restrict__ xb) {
    const size_t i = ((size_t)blockIdx.x * 256 + threadIdx.x) * 8;
    const float4 v0 = *(const float4*)(x + i);
    const float4 v1 = *(const float4*)(x + i + 4);
    uint4 p;
    p.x = (unsigned)f2bf(v0.x) | ((unsigned)f2bf(v0.y) << 16);
    p.y = (unsigned)f2bf(v0.z) | ((unsigned)f2bf(v0.w) << 16);
    p.z = (unsigned)f2bf(v1.x) | ((unsigned)f2bf(v1.y) << 16);
    p.w = (unsigned)f2bf(v1.z) | ((unsigned)f2bf(v1.w) << 16);
    *(uint4*)(xb + i) = p;
}

// ---------------- kernel: router (thread per token) ----------------
__global__ __launch_bounds__(128) void router2(
    const float* __restrict__ x, const float* __restrict__ rw,
    const float* __restrict__ rb, unsigned* __restrict__ cnt,
    unsigned* __restrict__ tok_list, float* __restrict__ w_list) {
    __shared__ unsigned lcnt[E];
    __shared__ unsigned gbase[E];
    const int tid = threadIdx.x;
    if (tid < E) lcnt[tid] = 0u;
    __syncthreads();

    const int t = blockIdx.x * 128 + tid;
    const float4* xr = (const float4*)(x + (size_t)t * D);
    float acc[E];
#pragma unroll
    for (int e = 0; e < E; ++e) acc[e] = 0.f;

    for (int i = 0; i < D / 4; ++i) {
        const float4 xv = xr[i];
        const float* wr = rw + (size_t)i * 4 * E;   // wave-uniform -> s_load
#pragma unroll
        for (int e = 0; e < E; ++e) {
            acc[e] += xv.x * wr[e] + xv.y * wr[E + e] + xv.z * wr[2 * E + e]
                    + xv.w * wr[3 * E + e];
        }
    }
#pragma unroll
    for (int e = 0; e < E; ++e) acc[e] += rb[e];

    int e0 = 0; float l0 = acc[0];
#pragma unroll
    for (int e = 1; e < E; ++e) if (acc[e] > l0) { l0 = acc[e]; e0 = e; }
    int e1 = -1; float l1 = -3.4e38f;
#pragma unroll
    for (int e = 0; e < E; ++e)
        if (e != e0 && acc[e] > l1) { l1 = acc[e]; e1 = e; }

    const float w0 = 1.f / (1.f + expf(l1 - l0));   // renorm top-2 softmax
    const float w1v = 1.f - w0;

    const unsigned r0 = atomicAdd(&lcnt[e0], 1u);
    const unsigned r1 = atomicAdd(&lcnt[e1], 1u);
    __syncthreads();
    if (tid < E) gbase[tid] = atomicAdd(&cnt[tid], lcnt[tid]);
    __syncthreads();
    const unsigned s0 = gbase[e0] + r0;
    const unsigned s1 = gbase[e1] + r1;
    tok_list[(size_t)e0 * B + s0] = (unsigned)t;  w_list[(size_t)e0 * B + s0] = w0;
    tok_list[(size_t)e1 * B + s1] = (unsigned)t;  w_list[(size_t)e1 * B + s1] = w1v;
}

// ---------------- kernel: pad per-expert lists to multiple of 128 ----------------
__global__ __launch_bounds__(128) void pad_counts(
    const unsigned* __restrict__ cnt, unsigned* __restrict__ cntp,
    unsigned* __restrict__ tok_list, float* __restrict__ w_list, int cap) {
    const int tid = threadIdx.x;
    for (int e = 0; e < E; ++e) {
        const unsigned c = cnt[e];
        unsigned p = (c + 127u) & ~127u;
        if (p > (unsigned)cap) p = (unsigned)cap;
        if (c + tid < p) {
            tok_list[(size_t)e * B + c + tid] = 0u;   // valid token, weight 0
            w_list[(size_t)e * B + c + tid] = 0.f;
        }
        if (tid == 0) cntp[e] = p;
    }
}

// ---------------- kernel: fp32 [R][C] -> packed bf16 [R/32][C][32] (per expert z) --
// out[(r>>5)*C*32 + c*32 + (r&31)] = bf16(in[r][c])
// This makes a K-chunk B-tile (16 output rows x 32 k) CONTIGUOUS in memory, so the
// stage kernel's global_load_lds coalesces to 1 segment instead of a 16-segment
// gather (the round-3 bottleneck: TA address-processing rate).
__global__ __launch_bounds__(256) void pack_bf16(
    const float* __restrict__ in, unsigned short* __restrict__ outp,
    int R, int C) {
    __shared__ unsigned short T[64][72];
    const int e = blockIdx.z;
    const int c0 = blockIdx.x * 64, r0 = blockIdx.y * 64;
    const float* ine = in + (size_t)e * R * C;
    unsigned short* oute = outp + (size_t)e * R * C;
    const int tid = threadIdx.x;
    const int rl = tid >> 2, cl = (tid & 3) * 16;

    const float* src = ine + (size_t)(r0 + rl) * C + c0 + cl;
    unsigned pk[8];
#pragma unroll
    for (int i = 0; i < 4; ++i) {
        const float4 v = *(const float4*)(src + i * 4);
        pk[2 * i]     = (unsigned)f2bf(v.x) | ((unsigned)f2bf(v.y) << 16);
        pk[2 * i + 1] = (unsigned)f2bf(v.z) | ((unsigned)f2bf(v.w) << 16);
    }
    *(uint4*)(&T[rl][cl])     = make_uint4(pk[0], pk[1], pk[2], pk[3]);
    *(uint4*)(&T[rl][cl + 8]) = make_uint4(pk[4], pk[5], pk[6], pk[7]);
    __syncthreads();

    unsigned po[8];
#pragma unroll
    for (int j = 0; j < 8; ++j) {
        po[j] = (unsigned)T[cl + 2 * j][rl] | ((unsigned)T[cl + 2 * j + 1][rl] << 16);
    }
    // 16 consecutive r-values starting r0+cl stay within one 32-block (cl%32 in {0,16})
    unsigned short* dst = oute + ((size_t)((r0 + cl) >> 5) * C + (c0 + rl)) * 32
                               + ((r0 + cl) & 31);
    *(uint4*)(dst)     = make_uint4(po[0], po[1], po[2], po[3]);
    *(uint4*)(dst + 8) = make_uint4(po[4], po[5], po[6], po[7]);
}

// ---------------- shared-memory layout for the stage kernel ----------------
struct alignas(16) StageBufs {
    unsigned short A[2][128 * 32];    // 2 x 8 KB
    unsigned short Bm[2][128 * 32];   // 2 x 8 KB
};
union SmemU {
    StageBufs st;
    unsigned short Ct[64 * CT_ST];    // 17.5 KB, aliases st (epilogue only)
};

// ---------------- kernel: pipeline stage ----------------
// blockIdx.y <  4 : gemm2 for expert e_r : out[tok] += wgt * (hb_r[slot] @ w2p^T + b2)
// blockIdx.y >= 4 : gemm1 for expert e_w : hb_w = relu(xb[tok] @ w1p^T + b1), packed
// Layouts (all chosen for 1-segment staging loads):
//   w1p: [e][D/32][H][32]   w2p: [e][H/32][D][32]   hb: [H/32][cap][32]
//   xb : [B][D] row-major (A gather by token remains 16-segment - irreducible)
__global__ __launch_bounds__(256, 4) void stage_kernel(
    const unsigned short* __restrict__ xb,
    const unsigned short* __restrict__ w1p, const unsigned short* __restrict__ w2p,
    const float* __restrict__ b1, const float* __restrict__ b2,
    const unsigned* __restrict__ cntp,
    const unsigned* __restrict__ tok_list, const float* __restrict__ w_list,
    unsigned short* __restrict__ hb_w, const unsigned short* __restrict__ hb_r,
    float* __restrict__ out, int e_w, int e_r, int cap) {
    __shared__ SmemU sm;
    __shared__ int   s_toks[128];
    __shared__ float s_wgts[128];
    const int tid = threadIdx.x, wv = tid >> 6, lane = tid & 63;
    const int ln = lane & 15, q = lane >> 4;
    const int wm = wv & 1, wn = wv >> 1;
    const int r4 = lane >> 2, pc = lane & 3;
    const int m0 = blockIdx.x * 128;
    const int dst0 = (wv * 2 + 0) * 512;   // wave-uniform LDS chunk offsets (shorts)
    const int dst1 = (wv * 2 + 1) * 512;
    const int qs  = q  ^ ((ln >> 1) & 3);  // swizzled read slot (lane-constant)
    const int pcs = pc ^ ((r4 >> 1) & 3);  // swizzled source slot (lane-constant)

    f32x4 acc[4][4];
#pragma unroll
    for (int i = 0; i < 4; ++i)
#pragma unroll
        for (int j = 0; j < 4; ++j) acc[i][j] = (f32x4){0.f, 0.f, 0.f, 0.f};

    if (blockIdx.y >= 4) {
        // ---------------- gemm1 ----------------
        if (e_w < 0) return;
        const int e = e_w;
        if ((unsigned)m0 >= cntp[e]) return;
        const int n0 = (blockIdx.y - 4) * 128;
        const size_t base = (size_t)e * B;
        constexpr int NT = D / 32;   // 16

        const unsigned ta0 = tok_list[base + m0 + (wv * 2 + 0) * 16 + r4];
        const unsigned ta1 = tok_list[base + m0 + (wv * 2 + 1) * 16 + r4];
        const unsigned short* ap0 = xb + (size_t)ta0 * D + pcs * 8;
        const unsigned short* ap1 = xb + (size_t)ta1 * D + pcs * 8;
        const unsigned short* w1e = w1p + (size_t)e * H * D;   // packed [D/32][H][32]
        const unsigned short* bp0 = w1e + (size_t)(n0 + (wv * 2 + 0) * 16 + r4) * 32 + pcs * 8;
        const unsigned short* bp1 = w1e + (size_t)(n0 + (wv * 2 + 1) * 16 + r4) * 32 + pcs * 8;
        const size_t bstep = (size_t)H * 32;   // shorts per K-chunk in w1p

        unsigned short *A0 = sm.st.A[0], *A1 = sm.st.A[1];
        unsigned short *B0 = sm.st.Bm[0], *B1 = sm.st.Bm[1];

        // prologue: stage tile 0
        dma16(ap0, A0 + dst0);  dma16(ap1, A0 + dst1);
        dma16(bp0, B0 + dst0);  dma16(bp1, B0 + dst1);

        for (int t = 0; t < NT; ++t) {
            asm volatile("s_waitcnt vmcnt(0)" ::: "memory");
            __builtin_amdgcn_s_barrier();
            asm volatile("" ::: "memory");
            if (t + 1 < NT) {
                const int ka = (t + 1) * 32;
                const size_t kb = (size_t)(t + 1) * bstep;
                dma16(ap0 + ka, A1 + dst0);  dma16(ap1 + ka, A1 + dst1);
                dma16(bp0 + kb, B1 + dst0);  dma16(bp1 + kb, B1 + dst1);
            }
            bf16x8 af[4], bfr[4];
#pragma unroll
            for (int i = 0; i < 4; ++i) {
                af[i]  = *(const bf16x8*)(A0 + (wm * 64 + i * 16 + ln) * 32 + qs * 8);
                bfr[i] = *(const bf16x8*)(B0 + (wn * 64 + i * 16 + ln) * 32 + qs * 8);
            }
            __builtin_amdgcn_s_setprio(1);
#pragma unroll
            for (int mt = 0; mt < 4; ++mt)
#pragma unroll
                for (int nt = 0; nt < 4; ++nt)
                    acc[mt][nt] = __builtin_amdgcn_mfma_f32_16x16x32_bf16(
                        af[mt], bfr[nt], acc[mt][nt], 0, 0, 0);
            __builtin_amdgcn_s_setprio(0);
            unsigned short* tp;
            tp = A0; A0 = A1; A1 = tp;
            tp = B0; B0 = B1; B1 = tp;
        }
        __syncthreads();   // all ds_reads done before Ct aliases the buffers

        // epilogue: bias+relu, stage 64-row chunks in LDS, then packed 64B-chunk
        // stores into hb_w[H/32][cap][32] (fully lane-contiguous 1KB per instr)
        float b1v[4];
#pragma unroll
        for (int nt = 0; nt < 4; ++nt)
            b1v[nt] = b1[(size_t)e * H + n0 + wn * 64 + nt * 16 + ln];

#pragma unroll
        for (int c = 0; c < 2; ++c) {
            if (wm == c) {
#pragma unroll
                for (int mt = 0; mt < 4; ++mt)
#pragma unroll
                    for (int nt = 0; nt < 4; ++nt)
#pragma unroll
                        for (int r = 0; r < 4; ++r) {
                            const int lr = mt * 16 + q * 4 + r;
                            float v = acc[mt][nt][r] + b1v[nt];
                            v = v > 0.f ? v : 0.f;
                            sm.Ct[lr * CT_ST + wn * 64 + nt * 16 + ln] = f2bf(v);
                        }
            }
            __syncthreads();
            {
                const int cc = wv;                   // h-chunk (32 cols) within tile
#pragma unroll
                for (int u = 0; u < 4; ++u) {
                    const int sr = u * 16 + (lane >> 2);
                    const unsigned short* csrc = sm.Ct + sr * CT_ST + cc * 32 + (lane & 3) * 8;
                    unsigned short* gdst = hb_w
                        + ((size_t)((n0 >> 5) + cc) * cap + (m0 + c * 64 + sr)) * 32
                        + (lane & 3) * 8;
                    *(uint4*)gdst = *(const uint4*)csrc;
                }
            }
            __syncthreads();
        }
    } else {
        // ---------------- gemm2 ----------------
        if (e_r < 0) return;
        const int e = e_r;
        if ((unsigned)m0 >= cntp[e]) return;
        const int n0 = blockIdx.y * 128;
        const size_t base = (size_t)e * B;
        constexpr int NT = H / 32;   // 64

        if (tid < 128) {
            s_toks[tid] = (int)tok_list[base + m0 + tid];
            s_wgts[tid] = w_list[base + m0 + tid];
        }
        // A from packed hb_r [H/32][cap][32]; B from packed w2p [H/32][D][32]
        const unsigned short* ap0 = hb_r + (size_t)(m0 + (wv * 2 + 0) * 16 + r4) * 32 + pcs * 8;
        const unsigned short* ap1 = hb_r + (size_t)(m0 + (wv * 2 + 1) * 16 + r4) * 32 + pcs * 8;
        const unsigned short* w2e = w2p + (size_t)e * D * H;
        const unsigned short* bp0 = w2e + (size_t)(n0 + (wv * 2 + 0) * 16 + r4) * 32 + pcs * 8;
        const unsigned short* bp1 = w2e + (size_t)(n0 + (wv * 2 + 1) * 16 + r4) * 32 + pcs * 8;
        const size_t astep = (size_t)cap * 32;   // shorts per K-chunk in hb
        const size_t bstep = (size_t)D * 32;     // shorts per K-chunk in w2p

        unsigned short *A0 = sm.st.A[0], *A1 = sm.st.A[1];
        unsigned short *B0 = sm.st.Bm[0], *B1 = sm.st.Bm[1];

        dma16(ap0, A0 + dst0);  dma16(ap1, A0 + dst1);
        dma16(bp0, B0 + dst0);  dma16(bp1, B0 + dst1);

        for (int t = 0; t < NT; ++t) {
            asm volatile("s_waitcnt vmcnt(0)" ::: "memory");
            __builtin_amdgcn_s_barrier();
            asm volatile("" ::: "memory");
            if (t + 1 < NT) {
                const size_t ka = (size_t)(t + 1) * astep;
                const size_t kb = (size_t)(t + 1) * bstep;
                dma16(ap0 + ka, A1 + dst0);  dma16(ap1 + ka, A1 + dst1);
                dma16(bp0 + kb, B1 + dst0);  dma16(bp1 + kb, B1 + dst1);
            }
            bf16x8 af[4], bfr[4];
#pragma unroll
            for (int i = 0; i < 4; ++i) {
                af[i]  = *(const bf16x8*)(A0 + (wm * 64 + i * 16 + ln) * 32 + qs * 8);
                bfr[i] = *(const bf16x8*)(B0 + (wn * 64 + i * 16 + ln) * 32 + qs * 8);
            }
            __builtin_amdgcn_s_setprio(1);
#pragma unroll
            for (int mt = 0; mt < 4; ++mt)
#pragma unroll
                for (int nt = 0; nt < 4; ++nt)
                    acc[mt][nt] = __builtin_amdgcn_mfma_f32_16x16x32_bf16(
                        af[mt], bfr[nt], acc[mt][nt], 0, 0, 0);
            __builtin_amdgcn_s_setprio(0);
            unsigned short* tp;
            tp = A0; A0 = A1; A1 = tp;
            tp = B0; B0 = B1; B1 = tp;
        }
        __syncthreads();

        float b2v[4];
#pragma unroll
        for (int nt = 0; nt < 4; ++nt)
            b2v[nt] = b2[(size_t)e * D + n0 + wn * 64 + nt * 16 + ln];

#pragma unroll
        for (int mt = 0; mt < 4; ++mt) {
#pragma unroll
            for (int r = 0; r < 4; ++r) {
                const int m = wm * 64 + mt * 16 + q * 4 + r;
                const float wgt = s_wgts[m];
                if (wgt != 0.f) {                 // skip pad rows (avoids token-0 RMW race)
                    const int tok = s_toks[m];
                    float* orow = out + (size_t)tok * D + n0 + wn * 64 + ln;
#pragma unroll
                    for (int nt = 0; nt < 4; ++nt)
                        orow[nt * 16] += wgt * (acc[mt][nt][r] + b2v[nt]);
                }
            }
        }
    }
}

// ---------------- launch ----------------
extern "C" void kernel_launch(void* const* d_in, const int* in_sizes, int n_in,
                              void* d_out, int out_size, void* d_ws, size_t ws_size,
                              hipStream_t stream) {
    const float* x  = (const float*)d_in[0];
    const float* rw = (const float*)d_in[1];
    const float* rb = (const float*)d_in[2];
    const float* w1 = (const float*)d_in[3];
    const float* b1 = (const float*)d_in[4];
    const float* w2 = (const float*)d_in[5];
    const float* b2 = (const float*)d_in[6];
    float* out = (float*)d_out;

    char* ws = (char*)d_ws;
    const size_t off_tok = 1024;
    const size_t off_wl  = off_tok + (size_t)E * B * 4;
    const size_t off_w1s = off_wl  + (size_t)E * B * 4;
    const size_t off_w2s = off_w1s + (size_t)E * D * H * 2;
    const size_t off_xb  = off_w2s + (size_t)E * D * H * 2;
    const size_t off_hb  = off_xb  + (size_t)B * D * 2;

    unsigned* cnt      = (unsigned*)ws;
    unsigned* cntp     = (unsigned*)(ws + 256);
    unsigned* tok_list = (unsigned*)(ws + off_tok);
    float*    w_list   = (float*)(ws + off_wl);
    unsigned short* w1s = (unsigned short*)(ws + off_w1s);
    unsigned short* w2s = (unsigned short*)(ws + off_w2s);
    unsigned short* xb  = (unsigned short*)(ws + off_xb);

    // workspace-driven config (deterministic per call -> graph-safe)
    const size_t rem = (ws_size > off_hb) ? (ws_size - off_hb) : 0;
    const size_t hrow = (size_t)H * 2;
    int cap; bool pipelined;
    {
        size_t cp = (rem / 2 / hrow) & ~(size_t)127;
        if (cp > 24576) cp = 24576;
        if (cp >= 20480) { pipelined = true; cap = (int)cp; }
        else {
            pipelined = false;
            size_t cs = (rem / hrow) & ~(size_t)127;
            if (cs > 24576) cs = 24576;
            cap = (int)cs;
        }
    }
    unsigned short* hb0 = (unsigned short*)(ws + off_hb);
    unsigned short* hb1 = pipelined ? hb0 + (size_t)cap * H : hb0;

    hipMemsetAsync(ws, 0, 1024, stream);                                  // counters
    hipMemsetAsync(d_out, 0, (size_t)out_size * sizeof(float), stream);   // fp32 zeros

    convert_x<<<(B * D) / 2048, 256, 0, stream>>>(x, xb);
    // packed weights: w1p [e][D/32][H][32], w2p [e][H/32][D][32]
    pack_bf16<<<dim3(H / 64, D / 64, E), 256, 0, stream>>>(w1, w1s, D, H);
    pack_bf16<<<dim3(D / 64, H / 64, E), 256, 0, stream>>>(w2, w2s, H, D);
    router2<<<B / 128, 128, 0, stream>>>(x, rw, rb, cnt, tok_list, w_list);
    pad_counts<<<1, 128, 0, stream>>>(cnt, cntp, tok_list, w_list, cap);

    const dim3 sgrid(cap / 128, 20);   // y<4: gemm2 (long blocks first), y>=4: gemm1
    if (pipelined) {
        for (int s = 0; s <= E; ++s) {
            unsigned short* hw = (s & 1) ? hb1 : hb0;
            unsigned short* hr = (s & 1) ? hb0 : hb1;
            stage_kernel<<<sgrid, 256, 0, stream>>>(
                xb, w1s, w2s, b1, b2, cntp, tok_list, w_list,
                hw, hr, out, (s < E) ? s : -1, (s > 0) ? s - 1 : -1, cap);
        }
    } else {
        for (int e = 0; e < E; ++e) {
            stage_kernel<<<sgrid, 256, 0, stream>>>(
                xb, w1s, w2s, b1, b2, cntp, tok_list, w_list,
                hb0, hb0, out, e, -1, cap);
            stage_kernel<<<sgrid, 256, 0, stream>>>(
                xb, w1s, w2s, b1, b2, cntp, tok_list, w_list,
                hb0, hb0, out, -1, e, cap);
        }
    }
}